// Round 2
// baseline (670503.613 us; speedup 1.0000x reference)
//
#include <hip/hip_runtime.h>
#include <hip/hip_bf16.h>
#include <math.h>

// Problem constants
#define SL 512
#define BS 64
#define EMB 400
#define NHID 1150
#define POOLF 1200
#define HID2 50
#define NCLS 2

#define CHUNK 32                 // timesteps per hoisted-GEMM chunk
#define NCHUNK (SL / CHUNK)
#define MC (CHUNK * BS)          // 2048 rows per chunk GEMM
#define N4MAX (4 * NHID)         // 4600

// Workspace layout (float offsets) — total ~14.7M floats ~= 59 MB
#define OFF_G   ((size_t)0)                                  // [2048][4600]
#define OFF_Y1  (OFF_G  + (size_t)MC * N4MAX)                // [2048][1150] ring
#define OFF_Y2  (OFF_Y1 + (size_t)MC * NHID)                 // [2048][1150] ring
#define OFF_HZ  (OFF_Y2 + (size_t)MC * NHID)                 // [64][1150] zeros
#define OFF_C   (OFF_HZ + (size_t)BS * NHID)                 // 6 x [64][1150]
#define OFF_PL  (OFF_C  + (size_t)6 * BS * NHID)             // pooled [64][1200]

__global__ __launch_bounds__(256) void zero_kernel(float* __restrict__ p, int n)
{
    int i = blockIdx.x * 256 + threadIdx.x;
    if (i < n) p[i] = 0.f;
}

// ---------------------------------------------------------------------------
// C[M,N] = A[M,K] @ B[K,N] + bias[N]   (row-major, fp32, LDS-tiled 64x64x16)
#define BM 64
#define BN 64
#define BK 16
__global__ __launch_bounds__(256) void gemm_bias(
    const float* __restrict__ A, const float* __restrict__ B,
    const float* __restrict__ bias, float* __restrict__ C,
    int M, int N, int K)
{
    __shared__ float As[BK][BM + 4];   // transposed: As[k][m]
    __shared__ float Bs[BK][BN + 4];

    const int tx = threadIdx.x, ty = threadIdx.y;      // 16 x 16
    const int tid = ty * 16 + tx;
    const int m0 = blockIdx.y * BM;
    const int n0 = blockIdx.x * BN;

    float acc[4][4] = {};

    for (int k0 = 0; k0 < K; k0 += BK) {
        #pragma unroll
        for (int i = 0; i < 4; ++i) {
            int idx = tid + i * 256;
            int m = idx >> 4;
            int k = idx & 15;
            float v = 0.f;
            if (k0 + k < K) v = A[(size_t)(m0 + m) * K + k0 + k];
            As[k][m] = v;
        }
        #pragma unroll
        for (int i = 0; i < 4; ++i) {
            int idx = tid + i * 256;
            int k = idx >> 6;
            int n = idx & 63;
            float v = 0.f;
            if ((k0 + k < K) && (n0 + n < N)) v = B[(size_t)(k0 + k) * N + n0 + n];
            Bs[k][n] = v;
        }
        __syncthreads();
        #pragma unroll
        for (int k = 0; k < BK; ++k) {
            float4 a  = *(const float4*)&As[k][ty * 4];
            float4 bv = *(const float4*)&Bs[k][tx * 4];
            acc[0][0] += a.x * bv.x; acc[0][1] += a.x * bv.y; acc[0][2] += a.x * bv.z; acc[0][3] += a.x * bv.w;
            acc[1][0] += a.y * bv.x; acc[1][1] += a.y * bv.y; acc[1][2] += a.y * bv.z; acc[1][3] += a.y * bv.w;
            acc[2][0] += a.z * bv.x; acc[2][1] += a.z * bv.y; acc[2][2] += a.z * bv.z; acc[2][3] += a.z * bv.w;
            acc[3][0] += a.w * bv.x; acc[3][1] += a.w * bv.y; acc[3][2] += a.w * bv.z; acc[3][3] += a.w * bv.w;
        }
        __syncthreads();
    }

    #pragma unroll
    for (int i = 0; i < 4; ++i) {
        int m = m0 + ty * 4 + i;
        if (m >= M) continue;
        #pragma unroll
        for (int j = 0; j < 4; ++j) {
            int n = n0 + tx * 4 + j;
            if (n < N) C[(size_t)m * N + n] = acc[i][j] + bias[n];
        }
    }
}

// Same GEMM but A rows are gathered from the embedding table: A[m][k] = emb[xp[m]][k]
__global__ __launch_bounds__(256) void gemm_bias_gather(
    const int* __restrict__ xp, const float* __restrict__ emb,
    const float* __restrict__ B, const float* __restrict__ bias,
    float* __restrict__ C, int M, int N, int K)
{
    __shared__ float As[BK][BM + 4];
    __shared__ float Bs[BK][BN + 4];

    const int tx = threadIdx.x, ty = threadIdx.y;
    const int tid = ty * 16 + tx;
    const int m0 = blockIdx.y * BM;
    const int n0 = blockIdx.x * BN;

    float acc[4][4] = {};

    for (int k0 = 0; k0 < K; k0 += BK) {
        #pragma unroll
        for (int i = 0; i < 4; ++i) {
            int idx = tid + i * 256;
            int m = idx >> 4;
            int k = idx & 15;
            float v = 0.f;
            if (k0 + k < K) v = emb[(size_t)xp[m0 + m] * EMB + k0 + k];
            As[k][m] = v;
        }
        #pragma unroll
        for (int i = 0; i < 4; ++i) {
            int idx = tid + i * 256;
            int k = idx >> 6;
            int n = idx & 63;
            float v = 0.f;
            if ((k0 + k < K) && (n0 + n < N)) v = B[(size_t)(k0 + k) * N + n0 + n];
            Bs[k][n] = v;
        }
        __syncthreads();
        #pragma unroll
        for (int k = 0; k < BK; ++k) {
            float4 a  = *(const float4*)&As[k][ty * 4];
            float4 bv = *(const float4*)&Bs[k][tx * 4];
            acc[0][0] += a.x * bv.x; acc[0][1] += a.x * bv.y; acc[0][2] += a.x * bv.z; acc[0][3] += a.x * bv.w;
            acc[1][0] += a.y * bv.x; acc[1][1] += a.y * bv.y; acc[1][2] += a.y * bv.z; acc[1][3] += a.y * bv.w;
            acc[2][0] += a.z * bv.x; acc[2][1] += a.z * bv.y; acc[2][2] += a.z * bv.z; acc[2][3] += a.z * bv.w;
            acc[3][0] += a.w * bv.x; acc[3][1] += a.w * bv.y; acc[3][2] += a.w * bv.z; acc[3][3] += a.w * bv.w;
        }
        __syncthreads();
    }

    #pragma unroll
    for (int i = 0; i < 4; ++i) {
        int m = m0 + ty * 4 + i;
        if (m >= M) continue;
        #pragma unroll
        for (int j = 0; j < 4; ++j) {
            int n = n0 + tx * 4 + j;
            if (n < N) C[(size_t)m * N + n] = acc[i][j] + bias[n];
        }
    }
}

// ---------------------------------------------------------------------------
// One LSTM timestep: g = Gt + hprev @ Wh; gates; write cnext, yt (= h).
__global__ __launch_bounds__(256) void lstm_step(
    const float* __restrict__ Gt,     // [64][4H]
    const float* __restrict__ Wh,     // [H][4H]
    const float* __restrict__ hprev,  // [64][H]
    const float* __restrict__ cprev,  // [64][H]
    float* __restrict__ cnext,        // [64][H]
    float* __restrict__ yt,           // [64][H]
    int H)
{
    int j = blockIdx.x * 16 + threadIdx.x;
    int b = blockIdx.y * 16 + threadIdx.y;
    if (j >= H) return;
    const int N4 = 4 * H;

    float ai = Gt[(size_t)b * N4 + j];
    float af = Gt[(size_t)b * N4 + H + j];
    float ag = Gt[(size_t)b * N4 + 2 * H + j];
    float ao = Gt[(size_t)b * N4 + 3 * H + j];

    const float* hp = hprev + (size_t)b * H;
    const float* w = Wh;
    #pragma unroll 4
    for (int k = 0; k < H; ++k) {
        float hk = hp[k];
        ai += hk * w[j];
        af += hk * w[H + j];
        ag += hk * w[2 * H + j];
        ao += hk * w[3 * H + j];
        w += N4;
    }

    float si = 1.f / (1.f + expf(-ai));
    float sf = 1.f / (1.f + expf(-af));
    float so = 1.f / (1.f + expf(-ao));
    float tg = tanhf(ag);
    float c  = sf * cprev[(size_t)b * H + j] + si * tg;
    float h  = so * tanhf(c);
    cnext[(size_t)b * H + j] = c;
    yt[(size_t)b * H + j]    = h;
}

// ---------------------------------------------------------------------------
// pooled[b] = [ y3[511,b,:], max_t y3[:,b,:], mean_t y3[:,b,:] ]
__global__ __launch_bounds__(256) void pool_kernel(
    const float* __restrict__ y3, float* __restrict__ pooled)
{
    int tid = blockIdx.x * 256 + threadIdx.x;
    if (tid >= BS * EMB) return;
    int b = tid / EMB;
    int f = tid - b * EMB;
    float last = y3[((size_t)(SL - 1) * BS + b) * EMB + f];
    float mx = -INFINITY, sum = 0.f;
    for (int t = 0; t < SL; ++t) {
        float v = y3[((size_t)t * BS + b) * EMB + f];
        mx = fmaxf(mx, v);
        sum += v;
    }
    pooled[b * POOLF + f]           = last;
    pooled[b * POOLF + EMB + f]     = mx;
    pooled[b * POOLF + 2 * EMB + f] = sum * (1.f / (float)SL);
}

// ---------------------------------------------------------------------------
// Per-(i,b) head: h1 = relu(pooled[b] @ HW1[dom[i]] + Hb1[dom[i]]);
// score[i,b,:] = h1 @ HW2[dom[i]] + Hb2[dom[i]]
__global__ __launch_bounds__(64) void head_kernel(
    const float* __restrict__ pooled,
    const float* __restrict__ HW1, const float* __restrict__ Hb1,
    const float* __restrict__ HW2, const float* __restrict__ Hb2,
    const int* __restrict__ domain, float* __restrict__ score)
{
    int i = blockIdx.x >> 6;       // 0..63
    int b = blockIdx.x & 63;       // 0..63
    int d = domain[i];

    __shared__ float pl[POOLF];
    __shared__ float h1[HID2];
    for (int f = threadIdx.x; f < POOLF; f += 64) pl[f] = pooled[b * POOLF + f];
    __syncthreads();

    int j = threadIdx.x;
    if (j < HID2) {
        float acc = Hb1[d * HID2 + j];
        const float* w = HW1 + (size_t)d * POOLF * HID2;
        for (int f = 0; f < POOLF; ++f) acc += pl[f] * w[(size_t)f * HID2 + j];
        h1[j] = fmaxf(acc, 0.f);
    }
    __syncthreads();
    if (j < NCLS) {
        float s = Hb2[d * NCLS + j];
        const float* w2 = HW2 + (size_t)d * HID2 * NCLS;
        for (int k = 0; k < HID2; ++k) s += h1[k] * w2[k * NCLS + j];
        score[((size_t)i * BS + b) * NCLS + j] = s;
    }
}

// ---------------------------------------------------------------------------
extern "C" void kernel_launch(void* const* d_in, const int* in_sizes, int n_in,
                              void* d_out, int out_size, void* d_ws, size_t ws_size,
                              hipStream_t stream)
{
    const int*   x      = (const int*)  d_in[0];
    const int*   domain = (const int*)  d_in[1];
    const float* emb    = (const float*)d_in[2];
    const float* Wx1    = (const float*)d_in[3];
    const float* Wh1    = (const float*)d_in[4];
    const float* b1     = (const float*)d_in[5];
    const float* Wx2    = (const float*)d_in[6];
    const float* Wh2    = (const float*)d_in[7];
    const float* b2     = (const float*)d_in[8];
    const float* Wx3    = (const float*)d_in[9];
    const float* Wh3    = (const float*)d_in[10];
    const float* b3     = (const float*)d_in[11];
    const float* HW1    = (const float*)d_in[12];
    const float* Hb1    = (const float*)d_in[13];
    const float* HW2    = (const float*)d_in[14];
    const float* Hb2    = (const float*)d_in[15];

    float* out   = (float*)d_out;
    float* score = out;                            // [4096][2]
    float* y3    = out + (size_t)BS * BS * NCLS;   // [512][64][400]

    float* ws     = (float*)d_ws;
    float* G      = ws + OFF_G;
    float* y1buf  = ws + OFF_Y1;
    float* y2buf  = ws + OFF_Y2;
    float* hz     = ws + OFF_HZ;
    float* cbase  = ws + OFF_C;
    float* pooled = ws + OFF_PL;

    // zero the shared "initial state" buffer (ws re-poisoned each timed call)
    zero_kernel<<<(BS * NHID + 255) / 256, 256, 0, stream>>>(hz, BS * NHID);

    // per-layer c-state ping-pong buffers, indexed by t parity
    float* cb[3][2];
    for (int l = 0; l < 3; ++l)
        for (int p = 0; p < 2; ++p)
            cb[l][p] = cbase + (size_t)(2 * l + p) * BS * NHID;

    const dim3 blk(16, 16);
    const dim3 ggrid_h((4 * NHID + BN - 1) / BN, MC / BM);   // 72 x 32
    const dim3 ggrid_e((4 * EMB  + BN - 1) / BN, MC / BM);   // 25 x 32
    const dim3 sgrid_h((NHID + 15) / 16, BS / 16);
    const dim3 sgrid_e((EMB  + 15) / 16, BS / 16);

    for (int chunk = 0; chunk < NCHUNK; ++chunk) {
        const int rowbase = chunk * MC;   // token-row offset

        // ---- Layer 1: gather-fused GEMM, then 32 steps into y1 ring ----
        gemm_bias_gather<<<ggrid_h, blk, 0, stream>>>(
            x + rowbase, emb, Wx1, b1, G, MC, 4 * NHID, EMB);
        for (int tl = 0; tl < CHUNK; ++tl) {
            int t = chunk * CHUNK + tl;
            const float* Gt    = G + (size_t)tl * BS * 4 * NHID;
            const float* hprev = (t == 0) ? hz : y1buf + (size_t)((tl - 1) & (CHUNK - 1)) * BS * NHID;
            const float* cprev = (t == 0) ? hz : cb[0][t & 1];
            float*       cnext = cb[0][(t & 1) ^ 1];
            float*       yt    = y1buf + (size_t)tl * BS * NHID;
            lstm_step<<<sgrid_h, blk, 0, stream>>>(Gt, Wh1, hprev, cprev, cnext, yt, NHID);
        }

        // ---- Layer 2 ----
        gemm_bias<<<ggrid_h, blk, 0, stream>>>(y1buf, Wx2, b2, G, MC, 4 * NHID, NHID);
        for (int tl = 0; tl < CHUNK; ++tl) {
            int t = chunk * CHUNK + tl;
            const float* Gt    = G + (size_t)tl * BS * 4 * NHID;
            const float* hprev = (t == 0) ? hz : y2buf + (size_t)((tl - 1) & (CHUNK - 1)) * BS * NHID;
            const float* cprev = (t == 0) ? hz : cb[1][t & 1];
            float*       cnext = cb[1][(t & 1) ^ 1];
            float*       yt    = y2buf + (size_t)tl * BS * NHID;
            lstm_step<<<sgrid_h, blk, 0, stream>>>(Gt, Wh2, hprev, cprev, cnext, yt, NHID);
        }

        // ---- Layer 3 (writes y3 directly into d_out) ----
        gemm_bias<<<ggrid_e, blk, 0, stream>>>(y2buf, Wx3, b3, G, MC, 4 * EMB, NHID);
        for (int tl = 0; tl < CHUNK; ++tl) {
            int t = chunk * CHUNK + tl;
            const float* Gt    = G + (size_t)tl * BS * 4 * EMB;
            const float* hprev = (t == 0) ? hz : y3 + (size_t)(t - 1) * BS * EMB;
            const float* cprev = (t == 0) ? hz : cb[2][t & 1];
            float*       cnext = cb[2][(t & 1) ^ 1];
            float*       yt    = y3 + (size_t)t * BS * EMB;
            lstm_step<<<sgrid_e, blk, 0, stream>>>(Gt, Wh3, hprev, cprev, cnext, yt, EMB);
        }
    }

    // pooling
    pool_kernel<<<(BS * EMB + 255) / 256, 256, 0, stream>>>(y3, pooled);

    // heads
    head_kernel<<<BS * BS, 64, 0, stream>>>(pooled, HW1, Hb1, HW2, Hb2, domain, score);
}

// Round 5
// 50853.033 us; speedup vs baseline: 13.1851x; 13.1851x over previous
//
#include <hip/hip_runtime.h>
#include <hip/hip_bf16.h>
#include <math.h>

// Problem constants
#define SL 512
#define BS 64
#define EMB 400
#define NHID 1150
#define POOLF 1200
#define HID2 50
#define NCLS 2

#define CHUNK 16                 // timesteps per hoisted-GEMM chunk
#define NCHUNK (SL / CHUNK)
#define MC (CHUNK * BS)          // 1024 rows per chunk GEMM
#define N4MAX (4 * NHID)         // 4600

// step-kernel K-split parameters
#define KSPAN_H 112              // NHID layers: ceil(1150/112) = 11 splits
#define KS_H 11
#define KSPAN_E 32               // L3: ceil(400/32) = 13 splits
#define KS_E 13

// Workspace layout (float offsets) — total ~11.5M floats ~= 46 MB
#define OFF_G   ((size_t)0)                                  // [1024][4600]
#define OFF_P   (OFF_G  + (size_t)MC * N4MAX)                // [13][64][4600] worst case
#define OFF_Y1  (OFF_P  + (size_t)KS_E * BS * N4MAX)
#define OFF_Y2  (OFF_Y1 + (size_t)MC * NHID)                 // [1024][1150] ring
#define OFF_HZ  (OFF_Y2 + (size_t)MC * NHID)                 // [64][1150] zeros
#define OFF_C   (OFF_HZ + (size_t)BS * NHID)                 // 6 x [64][1150]
#define OFF_PL  (OFF_C  + (size_t)6 * BS * NHID)             // pooled [64][1200]

__global__ __launch_bounds__(256) void zero_kernel(float* __restrict__ p, int n)
{
    int i = blockIdx.x * 256 + threadIdx.x;
    if (i < n) p[i] = 0.f;
}

// ---------------------------------------------------------------------------
// C[M,N] = A[M,K] @ B[K,N] + bias[N]; tile 128x64x16, 8x4 per thread.
// Requires M % 128 == 0.
#define GBM 128
#define GBN 64
#define GBK 16
__global__ __launch_bounds__(256) void gemm_bias(
    const float* __restrict__ A, const float* __restrict__ B,
    const float* __restrict__ bias, float* __restrict__ C,
    int M, int N, int K)
{
    __shared__ float As[GBK][GBM + 4];   // As[k][m]
    __shared__ float Bs[GBK][GBN + 4];   // Bs[k][n]

    const int tid = threadIdx.x;
    const int tx = tid & 15;             // n-group: 4 cols each
    const int ty = tid >> 4;             // m-group: 8 rows each
    const int m0 = blockIdx.y * GBM;
    const int n0 = blockIdx.x * GBN;

    float acc[8][4] = {};

    const int ktiles = (K + GBK - 1) / GBK;
    for (int kt = 0; kt < ktiles; ++kt) {
        const int k0 = kt * GBK;
        // A tile 128x16: 512 float4, 2 per thread
        #pragma unroll
        for (int i = 0; i < 2; ++i) {
            int idx = tid + i * 256;
            int m = idx >> 2, q = idx & 3;
            int k = q * 4;
            const float* ap = A + (size_t)(m0 + m) * K + k0 + k;
            float4 v = make_float4(0.f, 0.f, 0.f, 0.f);
            if (k0 + k + 3 < K) v = *(const float4*)ap;
            else {
                if (k0 + k     < K) v.x = ap[0];
                if (k0 + k + 1 < K) v.y = ap[1];
                if (k0 + k + 2 < K) v.z = ap[2];
                if (k0 + k + 3 < K) v.w = ap[3];
            }
            As[k + 0][m] = v.x; As[k + 1][m] = v.y; As[k + 2][m] = v.z; As[k + 3][m] = v.w;
        }
        // B tile 16x64: 256 float4, 1 per thread
        {
            int k = tid >> 4, nq = tid & 15;
            int n = nq * 4;
            float4 v = make_float4(0.f, 0.f, 0.f, 0.f);
            if (k0 + k < K) {
                const float* bp = B + (size_t)(k0 + k) * N + n0 + n;
                if (n0 + n + 3 < N) v = *(const float4*)bp;
                else {
                    if (n0 + n     < N) v.x = bp[0];
                    if (n0 + n + 1 < N) v.y = bp[1];
                    if (n0 + n + 2 < N) v.z = bp[2];
                    if (n0 + n + 3 < N) v.w = bp[3];
                }
            }
            Bs[k][n + 0] = v.x; Bs[k][n + 1] = v.y; Bs[k][n + 2] = v.z; Bs[k][n + 3] = v.w;
        }
        __syncthreads();
        #pragma unroll
        for (int k = 0; k < GBK; ++k) {
            float4 a0 = *(const float4*)&As[k][ty * 8];
            float4 a1 = *(const float4*)&As[k][ty * 8 + 4];
            float4 b  = *(const float4*)&Bs[k][tx * 4];
            float av[8] = {a0.x, a0.y, a0.z, a0.w, a1.x, a1.y, a1.z, a1.w};
            float bv[4] = {b.x, b.y, b.z, b.w};
            #pragma unroll
            for (int r = 0; r < 8; ++r)
                #pragma unroll
                for (int c = 0; c < 4; ++c)
                    acc[r][c] += av[r] * bv[c];
        }
        __syncthreads();
    }

    #pragma unroll
    for (int r = 0; r < 8; ++r) {
        int m = m0 + ty * 8 + r;
        #pragma unroll
        for (int c = 0; c < 4; ++c) {
            int n = n0 + tx * 4 + c;
            if (n < N) C[(size_t)m * N + n] = acc[r][c] + bias[n];
        }
    }
}

// Same GEMM but A rows gathered from embedding: A[m][k] = emb[xp[m]][k] (K=EMB)
__global__ __launch_bounds__(256) void gemm_bias_gather(
    const int* __restrict__ xp, const float* __restrict__ emb,
    const float* __restrict__ B, const float* __restrict__ bias,
    float* __restrict__ C, int M, int N, int K)
{
    __shared__ float As[GBK][GBM + 4];
    __shared__ float Bs[GBK][GBN + 4];

    const int tid = threadIdx.x;
    const int tx = tid & 15;
    const int ty = tid >> 4;
    const int m0 = blockIdx.y * GBM;
    const int n0 = blockIdx.x * GBN;

    float acc[8][4] = {};

    const int ktiles = (K + GBK - 1) / GBK;
    for (int kt = 0; kt < ktiles; ++kt) {
        const int k0 = kt * GBK;
        #pragma unroll
        for (int i = 0; i < 2; ++i) {
            int idx = tid + i * 256;
            int m = idx >> 2, q = idx & 3;
            int k = q * 4;
            const float* ap = emb + (size_t)xp[m0 + m] * EMB + k0 + k;
            float4 v = make_float4(0.f, 0.f, 0.f, 0.f);
            if (k0 + k + 3 < K) v = *(const float4*)ap;
            else {
                if (k0 + k     < K) v.x = ap[0];
                if (k0 + k + 1 < K) v.y = ap[1];
                if (k0 + k + 2 < K) v.z = ap[2];
                if (k0 + k + 3 < K) v.w = ap[3];
            }
            As[k + 0][m] = v.x; As[k + 1][m] = v.y; As[k + 2][m] = v.z; As[k + 3][m] = v.w;
        }
        {
            int k = tid >> 4, nq = tid & 15;
            int n = nq * 4;
            float4 v = make_float4(0.f, 0.f, 0.f, 0.f);
            if (k0 + k < K) {
                const float* bp = B + (size_t)(k0 + k) * N + n0 + n;
                if (n0 + n + 3 < N) v = *(const float4*)bp;
                else {
                    if (n0 + n     < N) v.x = bp[0];
                    if (n0 + n + 1 < N) v.y = bp[1];
                    if (n0 + n + 2 < N) v.z = bp[2];
                    if (n0 + n + 3 < N) v.w = bp[3];
                }
            }
            Bs[k][n + 0] = v.x; Bs[k][n + 1] = v.y; Bs[k][n + 2] = v.z; Bs[k][n + 3] = v.w;
        }
        __syncthreads();
        #pragma unroll
        for (int k = 0; k < GBK; ++k) {
            float4 a0 = *(const float4*)&As[k][ty * 8];
            float4 a1 = *(const float4*)&As[k][ty * 8 + 4];
            float4 b  = *(const float4*)&Bs[k][tx * 4];
            float av[8] = {a0.x, a0.y, a0.z, a0.w, a1.x, a1.y, a1.z, a1.w};
            float bv[4] = {b.x, b.y, b.z, b.w};
            #pragma unroll
            for (int r = 0; r < 8; ++r)
                #pragma unroll
                for (int c = 0; c < 4; ++c)
                    acc[r][c] += av[r] * bv[c];
        }
        __syncthreads();
    }

    #pragma unroll
    for (int r = 0; r < 8; ++r) {
        int m = m0 + ty * 8 + r;
        #pragma unroll
        for (int c = 0; c < 4; ++c) {
            int n = n0 + tx * 4 + c;
            if (n < N) C[(size_t)m * N + n] = acc[r][c] + bias[n];
        }
    }
}

// ---------------------------------------------------------------------------
// Partial h@Wh for cols [n0,n0+128) and K-range [kb, kb+kspan).
// P[blockIdx.y][64][N] gets the partial tile (plain stores, no atomics).
#define SBM 64
#define SBN 128
#define SBK 16
__global__ __launch_bounds__(256) void step_partial(
    const float* __restrict__ hprev,  // [64][K]
    const float* __restrict__ Wh,     // [K][N]
    float* __restrict__ P,            // [KS][64][N]
    int N, int K, int kspan)
{
    __shared__ float Hs[SBK][SBM + 4];   // Hs[k][b]
    __shared__ float Ws[SBK][SBN + 4];   // Ws[k][n]

    const int tid = threadIdx.x;
    const int tx = tid & 31;             // n-group: 4 cols each (128 total)
    const int ty = tid >> 5;             // m-group: 8 rows each (64 total)
    const int n0 = blockIdx.x * SBN;
    const int kb = blockIdx.y * kspan;
    const int ke = min(kb + kspan, K);

    float acc[8][4] = {};

    for (int k0 = kb; k0 < ke; k0 += SBK) {
        // h tile 64x16: 256 float4, 1 per thread
        {
            int m = tid >> 2, q = tid & 3;
            int k = k0 + q * 4;
            const float* hp = hprev + (size_t)m * K + k;
            float4 v = make_float4(0.f, 0.f, 0.f, 0.f);
            if (k + 3 < ke) v = *(const float4*)hp;
            else {
                if (k     < ke) v.x = hp[0];
                if (k + 1 < ke) v.y = hp[1];
                if (k + 2 < ke) v.z = hp[2];
                if (k + 3 < ke) v.w = hp[3];
            }
            Hs[q * 4 + 0][m] = v.x; Hs[q * 4 + 1][m] = v.y;
            Hs[q * 4 + 2][m] = v.z; Hs[q * 4 + 3][m] = v.w;
        }
        // Wh tile 16x128: 512 float4, 2 per thread
        #pragma unroll
        for (int i = 0; i < 2; ++i) {
            int idx = tid + i * 256;
            int kk = idx >> 5, nq = idx & 31;
            int n = n0 + nq * 4;
            float4 v = make_float4(0.f, 0.f, 0.f, 0.f);
            if (k0 + kk < ke) {
                const float* wp = Wh + (size_t)(k0 + kk) * N + n;
                if (n + 3 < N) v = *(const float4*)wp;
                else {
                    if (n     < N) v.x = wp[0];
                    if (n + 1 < N) v.y = wp[1];
                    if (n + 2 < N) v.z = wp[2];
                    if (n + 3 < N) v.w = wp[3];
                }
            }
            Ws[kk][nq * 4 + 0] = v.x; Ws[kk][nq * 4 + 1] = v.y;
            Ws[kk][nq * 4 + 2] = v.z; Ws[kk][nq * 4 + 3] = v.w;
        }
        __syncthreads();
        #pragma unroll
        for (int k = 0; k < SBK; ++k) {
            float4 a0 = *(const float4*)&Hs[k][ty * 8];
            float4 a1 = *(const float4*)&Hs[k][ty * 8 + 4];
            float4 b  = *(const float4*)&Ws[k][tx * 4];
            float av[8] = {a0.x, a0.y, a0.z, a0.w, a1.x, a1.y, a1.z, a1.w};
            float bv[4] = {b.x, b.y, b.z, b.w};
            #pragma unroll
            for (int r = 0; r < 8; ++r)
                #pragma unroll
                for (int c = 0; c < 4; ++c)
                    acc[r][c] += av[r] * bv[c];
        }
        __syncthreads();
    }

    float* Ps = P + (size_t)blockIdx.y * SBM * N;
    #pragma unroll
    for (int r = 0; r < 8; ++r) {
        int m = ty * 8 + r;
        #pragma unroll
        for (int c = 0; c < 4; ++c) {
            int n = n0 + tx * 4 + c;
            if (n < N) Ps[(size_t)m * N + n] = acc[r][c];
        }
    }
}

// ---------------------------------------------------------------------------
// g = Gt + sum_s P[s]; gates; write cnext, yt.
__global__ __launch_bounds__(256) void lstm_gate(
    const float* __restrict__ Gt,     // [64][4H]
    const float* __restrict__ P,      // [KS][64][4H]
    int KS,
    const float* __restrict__ cprev,  // [64][H]
    float* __restrict__ cnext,        // [64][H]
    float* __restrict__ yt,           // [64][H]
    int H)
{
    int idx = blockIdx.x * 256 + threadIdx.x;
    if (idx >= BS * H) return;
    int b = idx / H;
    int j = idx - b * H;
    const int N = 4 * H;
    const size_t base = (size_t)b * N;

    float ai = Gt[base + j];
    float af = Gt[base + H + j];
    float ag = Gt[base + 2 * H + j];
    float ao = Gt[base + 3 * H + j];
    for (int s = 0; s < KS; ++s) {
        const float* Ps = P + (size_t)s * BS * N + base;
        ai += Ps[j];
        af += Ps[H + j];
        ag += Ps[2 * H + j];
        ao += Ps[3 * H + j];
    }

    float si = 1.f / (1.f + expf(-ai));
    float sf = 1.f / (1.f + expf(-af));
    float so = 1.f / (1.f + expf(-ao));
    float tg = tanhf(ag);
    float c  = sf * cprev[(size_t)b * H + j] + si * tg;
    float h  = so * tanhf(c);
    cnext[(size_t)b * H + j] = c;
    yt[(size_t)b * H + j]    = h;
}

// ---------------------------------------------------------------------------
__global__ __launch_bounds__(256) void pool_kernel(
    const float* __restrict__ y3, float* __restrict__ pooled)
{
    int tid = blockIdx.x * 256 + threadIdx.x;
    if (tid >= BS * EMB) return;
    int b = tid / EMB;
    int f = tid - b * EMB;
    float last = y3[((size_t)(SL - 1) * BS + b) * EMB + f];
    float mx = -INFINITY, sum = 0.f;
    for (int t = 0; t < SL; ++t) {
        float v = y3[((size_t)t * BS + b) * EMB + f];
        mx = fmaxf(mx, v);
        sum += v;
    }
    pooled[b * POOLF + f]           = last;
    pooled[b * POOLF + EMB + f]     = mx;
    pooled[b * POOLF + 2 * EMB + f] = sum * (1.f / (float)SL);
}

// ---------------------------------------------------------------------------
__global__ __launch_bounds__(64) void head_kernel(
    const float* __restrict__ pooled,
    const float* __restrict__ HW1, const float* __restrict__ Hb1,
    const float* __restrict__ HW2, const float* __restrict__ Hb2,
    const int* __restrict__ domain, float* __restrict__ score)
{
    int i = blockIdx.x >> 6;
    int b = blockIdx.x & 63;
    int d = domain[i];

    __shared__ float pl[POOLF];
    __shared__ float h1[HID2];
    for (int f = threadIdx.x; f < POOLF; f += 64) pl[f] = pooled[b * POOLF + f];
    __syncthreads();

    int j = threadIdx.x;
    if (j < HID2) {
        float acc = Hb1[d * HID2 + j];
        const float* w = HW1 + (size_t)d * POOLF * HID2;
        for (int f = 0; f < POOLF; ++f) acc += pl[f] * w[(size_t)f * HID2 + j];
        h1[j] = fmaxf(acc, 0.f);
    }
    __syncthreads();
    if (j < NCLS) {
        float s = Hb2[d * NCLS + j];
        const float* w2 = HW2 + (size_t)d * HID2 * NCLS;
        for (int k = 0; k < HID2; ++k) s += h1[k] * w2[k * NCLS + j];
        score[((size_t)i * BS + b) * NCLS + j] = s;
    }
}

// ---------------------------------------------------------------------------
extern "C" void kernel_launch(void* const* d_in, const int* in_sizes, int n_in,
                              void* d_out, int out_size, void* d_ws, size_t ws_size,
                              hipStream_t stream)
{
    const int*   x      = (const int*)  d_in[0];
    const int*   domain = (const int*)  d_in[1];
    const float* emb    = (const float*)d_in[2];
    const float* Wx1    = (const float*)d_in[3];
    const float* Wh1    = (const float*)d_in[4];
    const float* b1     = (const float*)d_in[5];
    const float* Wx2    = (const float*)d_in[6];
    const float* Wh2    = (const float*)d_in[7];
    const float* b2     = (const float*)d_in[8];
    const float* Wx3    = (const float*)d_in[9];
    const float* Wh3    = (const float*)d_in[10];
    const float* b3     = (const float*)d_in[11];
    const float* HW1    = (const float*)d_in[12];
    const float* Hb1    = (const float*)d_in[13];
    const float* HW2    = (const float*)d_in[14];
    const float* Hb2    = (const float*)d_in[15];

    float* out   = (float*)d_out;
    float* score = out;                            // [4096][2]
    float* y3    = out + (size_t)BS * BS * NCLS;   // [512][64][400]

    float* ws     = (float*)d_ws;
    float* G      = ws + OFF_G;
    float* P      = ws + OFF_P;
    float* y1buf  = ws + OFF_Y1;
    float* y2buf  = ws + OFF_Y2;
    float* hz     = ws + OFF_HZ;
    float* cbase  = ws + OFF_C;
    float* pooled = ws + OFF_PL;

    zero_kernel<<<(BS * NHID + 255) / 256, 256, 0, stream>>>(hz, BS * NHID);

    float* cb[3][2];
    for (int l = 0; l < 3; ++l)
        for (int p = 0; p < 2; ++p)
            cb[l][p] = cbase + (size_t)(2 * l + p) * BS * NHID;

    const dim3 ggrid_h((4 * NHID + GBN - 1) / GBN, MC / GBM);   // 72 x 8
    const dim3 ggrid_e((4 * EMB  + GBN - 1) / GBN, MC / GBM);   // 25 x 8
    const dim3 pgrid_h((4 * NHID + SBN - 1) / SBN, KS_H);       // 36 x 11
    const dim3 pgrid_e((4 * EMB  + SBN - 1) / SBN, KS_E);       // 13 x 13
    const int  ggate_h = (BS * NHID + 255) / 256;
    const int  ggate_e = (BS * EMB  + 255) / 256;

    for (int chunk = 0; chunk < NCHUNK; ++chunk) {
        const int rowbase = chunk * MC;

        // ---- Layer 1: gather-fused GEMM + 16 steps ----
        gemm_bias_gather<<<ggrid_h, 256, 0, stream>>>(
            x + rowbase, emb, Wx1, b1, G, MC, 4 * NHID, EMB);
        for (int tl = 0; tl < CHUNK; ++tl) {
            int t = chunk * CHUNK + tl;
            const float* Gt    = G + (size_t)tl * BS * 4 * NHID;
            const float* hprev = (t == 0) ? hz : y1buf + (size_t)((tl - 1) & (CHUNK - 1)) * BS * NHID;
            const float* cprev = (t == 0) ? hz : cb[0][t & 1];
            float*       cnext = cb[0][(t & 1) ^ 1];
            float*       yt    = y1buf + (size_t)tl * BS * NHID;
            step_partial<<<pgrid_h, 256, 0, stream>>>(hprev, Wh1, P, 4 * NHID, NHID, KSPAN_H);
            lstm_gate<<<ggate_h, 256, 0, stream>>>(Gt, P, KS_H, cprev, cnext, yt, NHID);
        }

        // ---- Layer 2 ----
        gemm_bias<<<ggrid_h, 256, 0, stream>>>(y1buf, Wx2, b2, G, MC, 4 * NHID, NHID);
        for (int tl = 0; tl < CHUNK; ++tl) {
            int t = chunk * CHUNK + tl;
            const float* Gt    = G + (size_t)tl * BS * 4 * NHID;
            const float* hprev = (t == 0) ? hz : y2buf + (size_t)((tl - 1) & (CHUNK - 1)) * BS * NHID;
            const float* cprev = (t == 0) ? hz : cb[1][t & 1];
            float*       cnext = cb[1][(t & 1) ^ 1];
            float*       yt    = y2buf + (size_t)tl * BS * NHID;
            step_partial<<<pgrid_h, 256, 0, stream>>>(hprev, Wh2, P, 4 * NHID, NHID, KSPAN_H);
            lstm_gate<<<ggate_h, 256, 0, stream>>>(Gt, P, KS_H, cprev, cnext, yt, NHID);
        }

        // ---- Layer 3 (y3 -> d_out) ----
        gemm_bias<<<ggrid_e, 256, 0, stream>>>(y2buf, Wx3, b3, G, MC, 4 * EMB, NHID);
        for (int tl = 0; tl < CHUNK; ++tl) {
            int t = chunk * CHUNK + tl;
            const float* Gt    = G + (size_t)tl * BS * 4 * EMB;
            const float* hprev = (t == 0) ? hz : y3 + (size_t)(t - 1) * BS * EMB;
            const float* cprev = (t == 0) ? hz : cb[2][t & 1];
            float*       cnext = cb[2][(t & 1) ^ 1];
            float*       yt    = y3 + (size_t)t * BS * EMB;
            step_partial<<<pgrid_e, 256, 0, stream>>>(hprev, Wh3, P, 4 * EMB, EMB, KSPAN_E);
            lstm_gate<<<ggate_e, 256, 0, stream>>>(Gt, P, KS_E, cprev, cnext, yt, EMB);
        }
    }

    pool_kernel<<<(BS * EMB + 255) / 256, 256, 0, stream>>>(y3, pooled);
    head_kernel<<<BS * BS, 64, 0, stream>>>(pooled, HW1, Hb1, HW2, Hb2, domain, score);
}